// Round 5
// baseline (83.116 us; speedup 1.0000x reference)
//
#include <hip/hip_runtime.h>
#include <hip/hip_bf16.h>

#define NHALF 4096
#define TWO_N 8192
#define DDIM 256
#define INV_T 10.0f
// 10 * log2(e): exp(10*s) = exp2(s * SCALE) where s is the raw cosine dot
#define SCALE 14.426950408889634f
#define NCHUNK 16   // column chunks of 512

typedef __bf16 v8bf __attribute__((ext_vector_type(8)));
typedef float f32x4 __attribute__((ext_vector_type(4)));

#if __has_builtin(__builtin_amdgcn_exp2f)
#define EXP2F(x) __builtin_amdgcn_exp2f(x)
#else
#define EXP2F(x) exp2f(x)
#endif

static __device__ __forceinline__ unsigned short f2bf(float x) {
    __hip_bfloat16 h = __float2bfloat16(x);
    return *(unsigned short*)&h;
}

// ---------------- kernel 1: normalize rows -> bf16 zn; also zero out ----------------
__global__ __launch_bounds__(256) void ntx_norm_kernel(
    const float* __restrict__ zi, const float* __restrict__ zj,
    __hip_bfloat16* __restrict__ zn, float* __restrict__ out) {
    const int w = threadIdx.x >> 6;
    const int lane = threadIdx.x & 63;
    const int r = blockIdx.x * 4 + w;
    const float* src = (r < NHALF) ? (zi + (size_t)r * DDIM)
                                   : (zj + (size_t)(r - NHALF) * DDIM);
    float4 v = ((const float4*)src)[lane];
    float ss = v.x * v.x + v.y * v.y + v.z * v.z + v.w * v.w;
#pragma unroll
    for (int m = 1; m < 64; m <<= 1) ss += __shfl_xor(ss, m);
    float rinv = 1.0f / fmaxf(sqrtf(ss), 1e-8f);
    ushort4 o;
    o.x = f2bf(v.x * rinv);
    o.y = f2bf(v.y * rinv);
    o.z = f2bf(v.z * rinv);
    o.w = f2bf(v.w * rinv);
    ((ushort4*)(zn + (size_t)r * DDIM))[lane] = o;
    if (blockIdx.x == 0 && threadIdx.x == 0) out[0] = 0.0f;
}

// ---------------- kernel 2: Gram + partial sum-of-exp ----------------
// grid = 32 row-blocks(256 rows) x 16 col-chunks(512 cols) = 512 blocks.
// 4 waves/block; wave w owns 64 rows (4 row-fragments of 16). A fragments
// (128 VGPRs) are PINNED via empty asm so the compiler cannot sink/remat the
// loads into the t-loop (round-4 failure: VGPR=104, A reloaded every tile ->
// 2.6 GB L2 traffic -> L2-BW-bound 76 us). B is dual-buffered in registers.
__global__ __launch_bounds__(256, 2) void ntx_gram_kernel(
    const __hip_bfloat16* __restrict__ zn,
    float* __restrict__ partial,   // [NCHUNK][TWO_N]
    float* __restrict__ spos) {    // [TWO_N]
    const int b = blockIdx.x;
    const int rblk = b >> 4;           // 0..31
    const int q = b & 15;              // col chunk 0..15
    const int w = threadIdx.x >> 6;    // wave 0..3
    const int lane = threadIdx.x & 63;
    const int wrbase = rblk * 256 + w * 64;   // wave's 64 rows

    const int lrow = lane & 15;        // row (A) / col (B, C/D)
    const int lk = lane >> 4;          // k-group 0..3

    const char* znb = (const char*)zn; // row stride = 512 B

    // A fragments for 4 row-tiles: zn[wrbase + rf*16 + lrow][kb*32 + lk*8 .. +7]
    f32x4 af[4][8];
#pragma unroll
    for (int rf = 0; rf < 4; ++rf) {
        const char* abase =
            znb + (((size_t)(wrbase + rf * 16 + lrow)) << 9) + (lk << 4);
#pragma unroll
        for (int kb = 0; kb < 8; ++kb)
            af[rf][kb] = *(const f32x4*)(abase + kb * 64);
    }
    // Pin: opaque def — compiler can't rematerialize, must keep resident.
#pragma unroll
    for (int rf = 0; rf < 4; ++rf)
#pragma unroll
        for (int kb = 0; kb < 8; ++kb)
            asm volatile("" : "+v"(af[rf][kb]));

    const int cq0 = q * 512;
    int dt[4], pt[4];
#pragma unroll
    for (int rf = 0; rf < 4; ++rf) {
        const int drow = wrbase + rf * 16;
        dt[rf] = (drow >= cq0 && drow < cq0 + 512) ? ((drow - cq0) >> 4) : -1;
        const int pcol = (drow + NHALF) & (TWO_N - 1);
        pt[rf] = (pcol >= cq0 && pcol < cq0 + 512) ? ((pcol - cq0) >> 4) : -1;
    }
    bool ondiag[4];
#pragma unroll
    for (int j = 0; j < 4; ++j) ondiag[j] = (lrow == lk * 4 + j);

    float sume[4][4];
#pragma unroll
    for (int rf = 0; rf < 4; ++rf)
#pragma unroll
        for (int j = 0; j < 4; ++j) sume[rf][j] = 0.0f;

#define LOADB(dst, tt)                                                        \
    do {                                                                      \
        const char* bbase =                                                   \
            znb + (((size_t)(cq0 + (tt) * 16 + lrow)) << 9) + (lk << 4);      \
        _Pragma("unroll")                                                     \
        for (int kb = 0; kb < 8; ++kb)                                        \
            dst[kb] = *(const f32x4*)(bbase + kb * 64);                       \
    } while (0)

#define COMPUTE(bf, tt)                                                       \
    do {                                                                      \
        f32x4 acc[4];                                                         \
        _Pragma("unroll")                                                     \
        for (int rf = 0; rf < 4; ++rf) acc[rf] = (f32x4){0.f, 0.f, 0.f, 0.f}; \
        _Pragma("unroll")                                                     \
        for (int kb = 0; kb < 8; ++kb) {                                      \
            _Pragma("unroll")                                                 \
            for (int rf = 0; rf < 4; ++rf)                                    \
                acc[rf] = __builtin_amdgcn_mfma_f32_16x16x32_bf16(            \
                    __builtin_bit_cast(v8bf, af[rf][kb]),                     \
                    __builtin_bit_cast(v8bf, bf[kb]), acc[rf], 0, 0, 0);      \
        }                                                                     \
        _Pragma("unroll")                                                     \
        for (int rf = 0; rf < 4; ++rf) {                                      \
            const bool isd = ((tt) == dt[rf]);                                \
            const bool isp = ((tt) == pt[rf]);                                \
            _Pragma("unroll")                                                 \
            for (int j = 0; j < 4; ++j) {                                     \
                const float s = acc[rf][j];                                   \
                if (isp && ondiag[j])                                         \
                    spos[wrbase + rf * 16 + lk * 4 + j] = s * INV_T;          \
                const float e = EXP2F(s * SCALE);                             \
                sume[rf][j] += (isd && ondiag[j]) ? 0.0f : e;                 \
            }                                                                 \
        }                                                                     \
    } while (0)

    f32x4 b0[8], b1[8];
    LOADB(b0, 0);
    for (int t = 0; t < 32; t += 2) {
        LOADB(b1, t + 1);          // prefetch t+1 while computing t
        COMPUTE(b0, t);
        if (t + 2 < 32) LOADB(b0, t + 2);  // prefetch t+2 while computing t+1
        COMPUTE(b1, t + 1);
    }
#undef LOADB
#undef COMPUTE

    // reduce across the 16 columns (lanes sharing lk differ in bits 0..3)
#pragma unroll
    for (int rf = 0; rf < 4; ++rf) {
#pragma unroll
        for (int j = 0; j < 4; ++j) {
            float v = sume[rf][j];
            v += __shfl_xor(v, 1);
            v += __shfl_xor(v, 2);
            v += __shfl_xor(v, 4);
            v += __shfl_xor(v, 8);
            if (lrow == 0)
                partial[(size_t)q * TWO_N + wrbase + rf * 16 + lk * 4 + j] = v;
        }
    }
}

// ---------------- kernel 3: finalize (out zeroed by kernel 1) ----------------
__global__ __launch_bounds__(256) void ntx_final_kernel(
    const float* __restrict__ partial, const float* __restrict__ spos,
    float* __restrict__ out) {
    const int tid = threadIdx.x;
    const int r = blockIdx.x * 256 + tid;
    float se = 0.0f;
#pragma unroll
    for (int c = 0; c < NCHUNK; ++c) se += partial[(size_t)c * TWO_N + r];
    float nll = logf(se) - spos[r];
    __shared__ float red[256];
    red[tid] = nll;
    __syncthreads();
    for (int s = 128; s > 0; s >>= 1) {
        if (tid < s) red[tid] += red[tid + s];
        __syncthreads();
    }
    if (tid == 0) atomicAdd(out, red[0] * (1.0f / (float)TWO_N));
}

extern "C" void kernel_launch(void* const* d_in, const int* in_sizes, int n_in,
                              void* d_out, int out_size, void* d_ws, size_t ws_size,
                              hipStream_t stream) {
    const float* zi = (const float*)d_in[0];
    const float* zj = (const float*)d_in[1];
    char* ws = (char*)d_ws;
    __hip_bfloat16* zn = (__hip_bfloat16*)ws;                          // 4 MB
    size_t off = (size_t)TWO_N * DDIM * 2;
    float* partial = (float*)(ws + off);                               // 512 KB
    off += (size_t)NCHUNK * TWO_N * 4;
    float* spos = (float*)(ws + off);                                  // 32 KB
    float* out = (float*)d_out;

    ntx_norm_kernel<<<TWO_N / 4, 256, 0, stream>>>(zi, zj, zn, out);
    ntx_gram_kernel<<<512, 256, 0, stream>>>(zn, partial, spos);
    ntx_final_kernel<<<TWO_N / 256, 256, 0, stream>>>(partial, spos, out);
}

// Round 6
// 59.392 us; speedup vs baseline: 1.3995x; 1.3995x over previous
//
#include <hip/hip_runtime.h>
#include <hip/hip_bf16.h>

#define NHALF 4096
#define TWO_N 8192
#define DDIM 256
#define INV_T 10.0f
// 10 * log2(e): exp(10*s) = exp2(s * SCALE) where s is the raw cosine dot
#define SCALE 14.426950408889634f
#define NCHUNK 16   // column chunks of 512

typedef __bf16 v8bf __attribute__((ext_vector_type(8)));
typedef float f32x4 __attribute__((ext_vector_type(4)));

#if __has_builtin(__builtin_amdgcn_exp2f)
#define EXP2F(x) __builtin_amdgcn_exp2f(x)
#else
#define EXP2F(x) exp2f(x)
#endif

static __device__ __forceinline__ unsigned short f2bf(float x) {
    __hip_bfloat16 h = __float2bfloat16(x);
    return *(unsigned short*)&h;
}

// ---------------- kernel 1: normalize rows -> bf16 zn; also zero out ----------------
__global__ __launch_bounds__(256) void ntx_norm_kernel(
    const float* __restrict__ zi, const float* __restrict__ zj,
    __hip_bfloat16* __restrict__ zn, float* __restrict__ out) {
    const int w = threadIdx.x >> 6;
    const int lane = threadIdx.x & 63;
    const int r = blockIdx.x * 4 + w;
    const float* src = (r < NHALF) ? (zi + (size_t)r * DDIM)
                                   : (zj + (size_t)(r - NHALF) * DDIM);
    float4 v = ((const float4*)src)[lane];
    float ss = v.x * v.x + v.y * v.y + v.z * v.z + v.w * v.w;
#pragma unroll
    for (int m = 1; m < 64; m <<= 1) ss += __shfl_xor(ss, m);
    float rinv = 1.0f / fmaxf(sqrtf(ss), 1e-8f);
    ushort4 o;
    o.x = f2bf(v.x * rinv);
    o.y = f2bf(v.y * rinv);
    o.z = f2bf(v.z * rinv);
    o.w = f2bf(v.w * rinv);
    ((ushort4*)(zn + (size_t)r * DDIM))[lane] = o;
    if (blockIdx.x == 0 && threadIdx.x == 0) out[0] = 0.0f;
}

// ---------------- kernel 2: Gram + partial sum-of-exp ----------------
// grid = 64 row-blocks(128 rows) x 16 col-chunks(512 cols) = 1024 blocks (4/CU).
// 4 waves/block; wave owns 32 rows (2 rf), A pinned in 64 regs for full K=256.
// B tile (16 cols x 512 B = contiguous 8 KB slab of zn) is staged via LDS:
//   coalesced 16B/thread global loads (issued one full iteration early, T14),
//   ds_write with XOR slot swizzle (slot ^= row&7) -> bank-uniform ds_read_b128.
// (R3-R5 failure mode: direct 512B-stride B gather = 16 cache lines per load
//  instr -> address-serialization + exposed latency at 2 waves/SIMD = 75 us.)
__global__ __launch_bounds__(256, 3) void ntx_gram_kernel(
    const __hip_bfloat16* __restrict__ zn,
    float* __restrict__ partial,   // [NCHUNK][TWO_N]
    float* __restrict__ spos) {    // [TWO_N]
    const int b = blockIdx.x;
    const int rblk = b >> 4;           // 0..63
    const int q = b & 15;              // col chunk 0..15
    const int tid = threadIdx.x;
    const int w = tid >> 6;            // wave 0..3
    const int lane = tid & 63;
    const int wrbase = rblk * 128 + w * 32;   // wave's 32 rows

    const int lrow = lane & 15;        // row (A) / col (B, C/D)
    const int lk = lane >> 4;          // k-group 0..3

    const char* znb = (const char*)zn; // row stride = 512 B

    __shared__ f32x4 ldsv[1024];       // 16 KB = two 8 KB buffers
    char* lds = (char*)ldsv;

    // A fragments for 2 row-tiles: zn[wrbase + rf*16 + lrow][kb*32 + lk*8 .. +7]
    f32x4 af[2][8];
#pragma unroll
    for (int rf = 0; rf < 2; ++rf) {
        const char* abase =
            znb + (((size_t)(wrbase + rf * 16 + lrow)) << 9) + (lk << 4);
#pragma unroll
        for (int kb = 0; kb < 8; ++kb)
            af[rf][kb] = *(const f32x4*)(abase + kb * 64);
    }
#pragma unroll
    for (int rf = 0; rf < 2; ++rf)
#pragma unroll
        for (int kb = 0; kb < 8; ++kb)
            asm volatile("" : "+v"(af[rf][kb]));  // pin: no remat/sink

    const int cq0 = q * 512;
    int dt[2], pt[2];
#pragma unroll
    for (int rf = 0; rf < 2; ++rf) {
        const int drow = wrbase + rf * 16;
        dt[rf] = (drow >= cq0 && drow < cq0 + 512) ? ((drow - cq0) >> 4) : -1;
        const int pcol = (drow + NHALF) & (TWO_N - 1);
        pt[rf] = (pcol >= cq0 && pcol < cq0 + 512) ? ((pcol - cq0) >> 4) : -1;
    }
    bool ondiag[4];
#pragma unroll
    for (int j = 0; j < 4; ++j) ondiag[j] = (lrow == lk * 4 + j);

    float sume[2][4];
#pragma unroll
    for (int rf = 0; rf < 2; ++rf)
#pragma unroll
        for (int j = 0; j < 4; ++j) sume[rf][j] = 0.0f;

    // staging thread->slot map: thread handles 16B slots j0=tid, j1=tid+256
    // of the row-major [16 rows][32 slots] tile; write swizzle slot^(row&7).
    const int r0 = tid >> 5, s0 = tid & 31;
    const int r1 = (tid + 256) >> 5, s1 = tid & 31;  // (tid+256)&31 == tid&31
    const int wr0 = r0 * 512 + ((s0 ^ (r0 & 7)) << 4);
    const int wr1 = r1 * 512 + ((s1 ^ (r1 & 7)) << 4);
    const int g0 = tid * 16;
    const int g1 = 4096 + tid * 16;
    const int rdbase = lrow * 512;
    const int rxor = lrow & 7;

#define LOADSTAGE(pa, pb, tt)                                                 \
    do {                                                                      \
        const char* src = znb + (((size_t)(cq0 + (tt) * 16)) << 9);           \
        pa = *(const f32x4*)(src + g0);                                       \
        pb = *(const f32x4*)(src + g1);                                       \
    } while (0)

#define WRITESTAGE(base, pa, pb)                                              \
    do {                                                                      \
        *(f32x4*)(lds + (base) + wr0) = pa;                                   \
        *(f32x4*)(lds + (base) + wr1) = pb;                                   \
    } while (0)

#define COMPUTE(base, tt)                                                     \
    do {                                                                      \
        const char* lb = lds + (base) + rdbase;                               \
        f32x4 bf[8];                                                          \
        _Pragma("unroll")                                                     \
        for (int kb = 0; kb < 8; ++kb)                                        \
            bf[kb] = *(const f32x4*)(lb + (((lk + 4 * kb) ^ rxor) << 4));     \
        f32x4 acc[2];                                                         \
        _Pragma("unroll")                                                     \
        for (int rf = 0; rf < 2; ++rf) acc[rf] = (f32x4){0.f, 0.f, 0.f, 0.f}; \
        _Pragma("unroll")                                                     \
        for (int kb = 0; kb < 8; ++kb) {                                      \
            _Pragma("unroll")                                                 \
            for (int rf = 0; rf < 2; ++rf)                                    \
                acc[rf] = __builtin_amdgcn_mfma_f32_16x16x32_bf16(            \
                    __builtin_bit_cast(v8bf, af[rf][kb]),                     \
                    __builtin_bit_cast(v8bf, bf[kb]), acc[rf], 0, 0, 0);      \
        }                                                                     \
        _Pragma("unroll")                                                     \
        for (int rf = 0; rf < 2; ++rf) {                                      \
            const bool isd = ((tt) == dt[rf]);                                \
            const bool isp = ((tt) == pt[rf]);                                \
            _Pragma("unroll")                                                 \
            for (int j = 0; j < 4; ++j) {                                     \
                const float s = acc[rf][j];                                   \
                if (isp && ondiag[j])                                         \
                    spos[wrbase + rf * 16 + lk * 4 + j] = s * INV_T;          \
                const float e = EXP2F(s * SCALE);                             \
                sume[rf][j] += (isd && ondiag[j]) ? 0.0f : e;                 \
            }                                                                 \
        }                                                                     \
    } while (0)

    f32x4 pA0, pA1, pB0, pB1;
    LOADSTAGE(pA0, pA1, 0);
    WRITESTAGE(0, pA0, pA1);
    LOADSTAGE(pB0, pB1, 1);
    __syncthreads();
#pragma unroll 1
    for (int t = 0; t < 32; t += 2) {
        if (t + 2 < 32) LOADSTAGE(pA0, pA1, t + 2);  // issue early (hide under MFMA)
        COMPUTE(0, t);
        WRITESTAGE(8192, pB0, pB1);                  // stage tile t+1
        __syncthreads();
        if (t + 3 < 32) LOADSTAGE(pB0, pB1, t + 3);
        COMPUTE(8192, t + 1);
        if (t + 2 < 32) WRITESTAGE(0, pA0, pA1);     // stage tile t+2
        __syncthreads();
    }
#undef LOADSTAGE
#undef WRITESTAGE
#undef COMPUTE

    // reduce across the 16 columns (lanes sharing lk differ in bits 0..3)
#pragma unroll
    for (int rf = 0; rf < 2; ++rf) {
#pragma unroll
        for (int j = 0; j < 4; ++j) {
            float v = sume[rf][j];
            v += __shfl_xor(v, 1);
            v += __shfl_xor(v, 2);
            v += __shfl_xor(v, 4);
            v += __shfl_xor(v, 8);
            if (lrow == 0)
                partial[(size_t)q * TWO_N + wrbase + rf * 16 + lk * 4 + j] = v;
        }
    }
}

// ---------------- kernel 3: finalize (out zeroed by kernel 1) ----------------
__global__ __launch_bounds__(256) void ntx_final_kernel(
    const float* __restrict__ partial, const float* __restrict__ spos,
    float* __restrict__ out) {
    const int tid = threadIdx.x;
    const int r = blockIdx.x * 256 + tid;
    float se = 0.0f;
#pragma unroll
    for (int c = 0; c < NCHUNK; ++c) se += partial[(size_t)c * TWO_N + r];
    float nll = logf(se) - spos[r];
    __shared__ float red[256];
    red[tid] = nll;
    __syncthreads();
    for (int s = 128; s > 0; s >>= 1) {
        if (tid < s) red[tid] += red[tid + s];
        __syncthreads();
    }
    if (tid == 0) atomicAdd(out, red[0] * (1.0f / (float)TWO_N));
}

extern "C" void kernel_launch(void* const* d_in, const int* in_sizes, int n_in,
                              void* d_out, int out_size, void* d_ws, size_t ws_size,
                              hipStream_t stream) {
    const float* zi = (const float*)d_in[0];
    const float* zj = (const float*)d_in[1];
    char* ws = (char*)d_ws;
    __hip_bfloat16* zn = (__hip_bfloat16*)ws;                          // 4 MB
    size_t off = (size_t)TWO_N * DDIM * 2;
    float* partial = (float*)(ws + off);                               // 512 KB
    off += (size_t)NCHUNK * TWO_N * 4;
    float* spos = (float*)(ws + off);                                  // 32 KB
    float* out = (float*)d_out;

    ntx_norm_kernel<<<TWO_N / 4, 256, 0, stream>>>(zi, zj, zn, out);
    ntx_gram_kernel<<<1024, 256, 0, stream>>>(zn, partial, spos);
    ntx_final_kernel<<<TWO_N / 256, 256, 0, stream>>>(partial, spos, out);
}

// Round 7
// 56.101 us; speedup vs baseline: 1.4815x; 1.0587x over previous
//
#include <hip/hip_runtime.h>
#include <hip/hip_bf16.h>

#define NHALF 4096
#define TWO_N 8192
#define DDIM 256
#define INV_T 10.0f
// 10 * log2(e): exp(10*s) = exp2(s * SCALE) where s is the raw cosine dot
#define SCALE 14.426950408889634f

typedef __bf16 v8bf __attribute__((ext_vector_type(8)));
typedef float f32x4 __attribute__((ext_vector_type(4)));

#if __has_builtin(__builtin_amdgcn_exp2f)
#define EXP2F(x) __builtin_amdgcn_exp2f(x)
#else
#define EXP2F(x) exp2f(x)
#endif

static __device__ __forceinline__ unsigned short f2bf(float x) {
    __hip_bfloat16 h = __float2bfloat16(x);
    return *(unsigned short*)&h;
}

// ---------------- kernel 1: normalize rows -> bf16 zn; zero rowacc & out ----
__global__ __launch_bounds__(256) void ntx_norm_kernel(
    const float* __restrict__ zi, const float* __restrict__ zj,
    __hip_bfloat16* __restrict__ zn, float* __restrict__ rowacc,
    float* __restrict__ out) {
    const int w = threadIdx.x >> 6;
    const int lane = threadIdx.x & 63;
    const int r = blockIdx.x * 4 + w;
    const float* src = (r < NHALF) ? (zi + (size_t)r * DDIM)
                                   : (zj + (size_t)(r - NHALF) * DDIM);
    float4 v = ((const float4*)src)[lane];
    float ss = v.x * v.x + v.y * v.y + v.z * v.z + v.w * v.w;
#pragma unroll
    for (int m = 1; m < 64; m <<= 1) ss += __shfl_xor(ss, m);
    float rinv = 1.0f / fmaxf(sqrtf(ss), 1e-8f);
    ushort4 o;
    o.x = f2bf(v.x * rinv);
    o.y = f2bf(v.y * rinv);
    o.z = f2bf(v.z * rinv);
    o.w = f2bf(v.w * rinv);
    ((ushort4*)(zn + (size_t)r * DDIM))[lane] = o;
    if (blockIdx.x < 32) rowacc[blockIdx.x * 256 + threadIdx.x] = 0.0f;
    if (blockIdx.x == 0 && threadIdx.x == 0) out[0] = 0.0f;
}

// ---------------- kernel 2: symmetric Gram + exp sums ----------------
// 32 row-groups of 256; blocks enumerate pairs (I >= J): 528 blocks.
// Block computes S[I-group][J-group] (256x256, K=256 in one pass).
// Row-sums -> rowacc[I-group rows]; for I!=J, col-sums (the mirrored tile's
// row-sums, by symmetry) -> rowacc[J-group rows]. Positives on local diag of
// I-J==16 blocks; true diagonal masked only in I==J blocks.
// 4 waves; wave owns 64 rows: af[4][8]=128 VGPRs pinned. Cols streamed in
// 8 chunks of 32 (16 KB LDS, XOR-swizzled, double-buffered, 1 barrier/chunk).
__global__ __launch_bounds__(256, 2) void ntx_gram_kernel(
    const __hip_bfloat16* __restrict__ zn,
    float* __restrict__ rowacc,    // [TWO_N] atomic accumulation
    float* __restrict__ spos) {    // [TWO_N]
    // triangle decode
    const int b = blockIdx.x;
    int I = (int)((sqrtf(8.0f * b + 1.0f) - 1.0f) * 0.5f);
    while ((I + 1) * (I + 2) / 2 <= b) ++I;
    while (I * (I + 1) / 2 > b) --I;
    const int J = b - I * (I + 1) / 2;
    const bool sameIJ = (I == J);
    const bool posblk = (I - J) == 16;
    const int Ibase = I * 256, Jbase = J * 256;

    const int tid = threadIdx.x;
    const int w = tid >> 6;
    const int lane = tid & 63;
    const int lrow = lane & 15;        // A-row / B-col / C-col within 16-tile
    const int lk = lane >> 4;          // k-group 0..3
    const int wr = w * 64;             // wave's local row base

    const char* znb = (const char*)zn; // row stride = 512 B

    __shared__ f32x4 ldsv[2112];       // 2 x 16KB chunk bufs + 1KB scol
    char* lds = (char*)ldsv;
    float* scol = (float*)(lds + 32768);
    scol[tid] = 0.0f;                  // col-sum accumulator (256 cols)

    // A fragments: zn[Ibase + wr + rf*16 + lrow][kb*32 + lk*8 .. +7]
    f32x4 af[4][8];
#pragma unroll
    for (int rf = 0; rf < 4; ++rf) {
        const char* abase =
            znb + (((size_t)(Ibase + wr + rf * 16 + lrow)) << 9) + (lk << 4);
#pragma unroll
        for (int kb = 0; kb < 8; ++kb)
            af[rf][kb] = *(const f32x4*)(abase + kb * 64);
    }
#pragma unroll
    for (int rf = 0; rf < 4; ++rf)
#pragma unroll
        for (int kb = 0; kb < 8; ++kb)
            asm volatile("" : "+v"(af[rf][kb]));  // pin: no remat/sink

    bool ondiag[4];
#pragma unroll
    for (int j = 0; j < 4; ++j) ondiag[j] = (lrow == lk * 4 + j);
    const int rdxor = lrow & 7;

    // staging map: thread writes 4 x 16B pieces of the 32-col (16KB) chunk.
    // piece p: row = (tid>>5)+p*8, slot = tid&31; write swizzle slot^(row&7).
    const int srow = tid >> 5, sslot = tid & 31;
    int wroff[4];
#pragma unroll
    for (int p = 0; p < 4; ++p) {
        const int rr = srow + p * 8;
        wroff[p] = rr * 512 + ((sslot ^ (rr & 7)) << 4);
    }

    float rowsum[4][4];
#pragma unroll
    for (int rf = 0; rf < 4; ++rf)
#pragma unroll
        for (int j = 0; j < 4; ++j) rowsum[rf][j] = 0.0f;

    // prologue: stage chunk 0 into buf 0
    f32x4 st[4];
    {
        const char* tb = znb + (((size_t)Jbase) << 9);
#pragma unroll
        for (int p = 0; p < 4; ++p)
            st[p] = *(const f32x4*)(tb + tid * 16 + p * 4096);
#pragma unroll
        for (int p = 0; p < 4; ++p)
            *(f32x4*)(lds + wroff[p]) = st[p];
    }
    __syncthreads();

#pragma unroll 1
    for (int ch = 0; ch < 8; ++ch) {
        const int cur = (ch & 1) << 14;          // 0 or 16384
        const int nxt = cur ^ 16384;
        if (ch + 1 < 8) {                        // issue next-chunk loads early
            const char* tb = znb + (((size_t)(Jbase + (ch + 1) * 32)) << 9);
#pragma unroll
            for (int p = 0; p < 4; ++p)
                st[p] = *(const f32x4*)(tb + tid * 16 + p * 4096);
        }

        // compute chunk ch from buf cur: 2 col-tiles x 4 row-tiles x 8 kb
        f32x4 acc[4][2];
#pragma unroll
        for (int rf = 0; rf < 4; ++rf)
#pragma unroll
            for (int cf = 0; cf < 2; ++cf) acc[rf][cf] = (f32x4){0.f, 0.f, 0.f, 0.f};
#pragma unroll
        for (int kb = 0; kb < 8; ++kb) {
            f32x4 bf[2];
#pragma unroll
            for (int cf = 0; cf < 2; ++cf)
                bf[cf] = *(const f32x4*)(lds + cur + (cf * 16 + lrow) * 512 +
                                         (((lk + 4 * kb) ^ rdxor) << 4));
#pragma unroll
            for (int rf = 0; rf < 4; ++rf)
#pragma unroll
                for (int cf = 0; cf < 2; ++cf)
                    acc[rf][cf] = __builtin_amdgcn_mfma_f32_16x16x32_bf16(
                        __builtin_bit_cast(v8bf, af[rf][kb]),
                        __builtin_bit_cast(v8bf, bf[cf]), acc[rf][cf], 0, 0, 0);
        }

        // epilogue: exp, row-sums, col-sums, spos/diag handling
        float ce0 = 0.0f, ce1 = 0.0f;
#pragma unroll
        for (int rf = 0; rf < 4; ++rf) {
            const int rurow = wr + rf * 16;      // local row base of this rf
#pragma unroll
            for (int cf = 0; cf < 2; ++cf) {
                const bool dm = (rurow == ch * 32 + cf * 16);  // wave-uniform
#pragma unroll
                for (int j = 0; j < 4; ++j) {
                    const float s = acc[rf][cf][j];
                    const bool od = dm && ondiag[j];
                    if (posblk && od) {
                        const int u = rurow + lk * 4 + j;
                        spos[Ibase + u] = s * INV_T;
                        spos[Jbase + u] = s * INV_T;
                    }
                    const float e = EXP2F(s * SCALE);
                    rowsum[rf][j] += (sameIJ && od) ? 0.0f : e;
                    if (cf == 0) ce0 += e; else ce1 += e;
                }
            }
        }
        if (!sameIJ) {
            ce0 += __shfl_xor(ce0, 16); ce0 += __shfl_xor(ce0, 32);
            ce1 += __shfl_xor(ce1, 16); ce1 += __shfl_xor(ce1, 32);
            if (lane < 16) {
                atomicAdd(&scol[ch * 32 + lrow], ce0);
                atomicAdd(&scol[ch * 32 + 16 + lrow], ce1);
            }
        }

        if (ch + 1 < 8) {                        // stage next chunk
#pragma unroll
            for (int p = 0; p < 4; ++p)
                *(f32x4*)(lds + nxt + wroff[p]) = st[p];
        }
        __syncthreads();
    }

    // flush row-sums (reduce over the 16 col-lanes)
#pragma unroll
    for (int rf = 0; rf < 4; ++rf) {
#pragma unroll
        for (int j = 0; j < 4; ++j) {
            float v = rowsum[rf][j];
            v += __shfl_xor(v, 1);
            v += __shfl_xor(v, 2);
            v += __shfl_xor(v, 4);
            v += __shfl_xor(v, 8);
            if (lrow == 0)
                atomicAdd(&rowacc[Ibase + wr + rf * 16 + lk * 4 + j], v);
        }
    }
    // flush col-sums (mirror contribution) for off-diagonal blocks
    if (!sameIJ) atomicAdd(&rowacc[Jbase + tid], scol[tid]);
}

// ---------------- kernel 3: finalize ----------------
__global__ __launch_bounds__(256) void ntx_final_kernel(
    const float* __restrict__ rowacc, const float* __restrict__ spos,
    float* __restrict__ out) {
    const int tid = threadIdx.x;
    const int r = blockIdx.x * 256 + tid;
    float nll = logf(rowacc[r]) - spos[r];
    __shared__ float red[256];
    red[tid] = nll;
    __syncthreads();
    for (int s = 128; s > 0; s >>= 1) {
        if (tid < s) red[tid] += red[tid + s];
        __syncthreads();
    }
    if (tid == 0) atomicAdd(out, red[0] * (1.0f / (float)TWO_N));
}

extern "C" void kernel_launch(void* const* d_in, const int* in_sizes, int n_in,
                              void* d_out, int out_size, void* d_ws, size_t ws_size,
                              hipStream_t stream) {
    const float* zi = (const float*)d_in[0];
    const float* zj = (const float*)d_in[1];
    char* ws = (char*)d_ws;
    __hip_bfloat16* zn = (__hip_bfloat16*)ws;                          // 4 MB
    size_t off = (size_t)TWO_N * DDIM * 2;
    float* spos = (float*)(ws + off);                                  // 32 KB
    off += (size_t)TWO_N * 4;
    float* rowacc = (float*)(ws + off);                                // 32 KB
    float* out = (float*)d_out;

    ntx_norm_kernel<<<TWO_N / 4, 256, 0, stream>>>(zi, zj, zn, rowacc, out);
    ntx_gram_kernel<<<528, 256, 0, stream>>>(zn, rowacc, spos);
    ntx_final_kernel<<<TWO_N / 256, 256, 0, stream>>>(rowacc, spos, out);
}